// Round 4
// baseline (2453.560 us; speedup 1.0000x reference)
//
#include <hip/hip_runtime.h>
#include <hip/hip_bf16.h>
#include <math.h>

// Problem constants
#define Bv 4
#define Sv 512
#define Dv 768
#define FFv 3072
#define Vv 30000
#define Vpad 30080
#define Hv 12
#define Mv 64
#define DHv 64
#define NLAYERS 12
#define QKVN 2304
#define MN (2048 * 768)

typedef __attribute__((ext_vector_type(8))) short short8;   // 8 bf16 (4 VGPRs)
typedef __attribute__((ext_vector_type(4))) float floatx4;  // MFMA accumulator

// fp32 -> bf16 (round to nearest even), returned as raw short bits
static __device__ __forceinline__ short f2b(float f) {
  union { float f; unsigned u; } v; v.f = f;
  unsigned r = v.u + 0x7fffu + ((v.u >> 16) & 1u);
  return (short)(r >> 16);
}

// async 16B global -> LDS (lds dest = wave-uniform base + lane*16)
#define GLD16(gp, lp) __builtin_amdgcn_global_load_lds( \
    (__attribute__((address_space(1))) void*)(gp), \
    (__attribute__((address_space(3))) void*)(lp), 16, 0, 0)

// ---------------- weight transpose+convert: W[K][N] f32 -> Wt[Nout][K] bf16 ----------------
__global__ __launch_bounds__(256) void transpose_w(
    const float* __restrict__ W, short* __restrict__ Wt,
    int K, int N, int Nout)
{
  __shared__ float t[32][33];
  int n0 = blockIdx.x * 32, k0 = blockIdx.y * 32;
  int tx = threadIdx.x & 31, ty = threadIdx.x >> 5;   // ty 0..7
  #pragma unroll
  for (int i = 0; i < 4; i++) {
    int k = k0 + ty + i * 8, n = n0 + tx;
    t[ty + i * 8][tx] = (n < N) ? W[(size_t)k * N + n] : 0.f;
  }
  __syncthreads();
  #pragma unroll
  for (int i = 0; i < 4; i++) {
    int n = n0 + ty + i * 8, k = k0 + tx;
    if (n < Nout) Wt[(size_t)n * K + k] = f2b(t[tx][ty + i * 8]);
  }
}

__global__ __launch_bounds__(256) void pack_bias(
    const float* __restrict__ bq, const float* __restrict__ bk,
    const float* __restrict__ bv, float* __restrict__ bqkv)
{
  int i = blockIdx.x * 256 + threadIdx.x;
  if (i < Dv) { bqkv[i] = bq[i]; bqkv[Dv + i] = bk[i]; bqkv[2 * Dv + i] = bv[i]; }
}

// ---------------- embedding: x = gather(se_w, tok) + se_b + pe ----------------
__global__ __launch_bounds__(256) void embed_kernel(
    const float* __restrict__ oh, const float* __restrict__ sew,
    const float* __restrict__ seb, float* __restrict__ xf,
    short* __restrict__ xb)
{
  int bs = blockIdx.x;            // b*S + s
  int s = bs & (Sv - 1);
  __shared__ int tokS;
  const float* row = oh + (size_t)bs * Vv;
  for (int j = threadIdx.x * 4; j < Vv; j += 256 * 4) {
    float4 f = *(const float4*)(row + j);
    if (f.x != 0.f) tokS = j;
    if (f.y != 0.f) tokS = j + 1;
    if (f.z != 0.f) tokS = j + 2;
    if (f.w != 0.f) tokS = j + 3;
  }
  __syncthreads();
  int tok = tokS;
  for (int d = threadIdx.x; d < Dv; d += 256) {
    float pe = 0.f;
    if (s > 0) {
      float denom = expf(9.210340371976184f * (2.f * (float)d / 768.f));
      float raw = (float)s / denom;
      pe = (d & 1) ? cosf(raw) : sinf(raw);
    }
    float val = sew[(size_t)tok * Dv + d] + seb[d] + pe;
    xf[(size_t)bs * Dv + d] = val;
    xb[(size_t)bs * Dv + d] = f2b(val);
  }
}

// ---------------- GEMM: C[M,N] = A[M,K]bf16 @ Bt[N,K]bf16^T + bias ----------------
// BMxBNx64 tiles, 4 waves in 2x2 (WM x WN each), global_load_lds staging with
// XOR-swizzled fetch mapping: chunk(row,kc) at LDS index row*8 + (kc^(row&7)).
// Split-K via gridDim.z: block z handles k in [z*klen, z*klen+klen), partial
// written to Cf + z*M*N. WVT: V-columns (col>=1536) of QKV output go to
// vt[bh*64+dh][s] (bf16 V^T) instead of Cb.
template <int BM, int BN, int WM, int WN, bool WVT>
__global__ __launch_bounds__(256) void gemm_bt(
    const short* __restrict__ A, const short* __restrict__ Bt,
    const float* __restrict__ bias, float* __restrict__ Cf,
    short* __restrict__ Cb, short* __restrict__ vt,
    int M, int N, int K, int klen, int relu)
{
  __shared__ __align__(16) short As[BM * 64];
  __shared__ __align__(16) short Bs[BN * 64];
  int n0 = blockIdx.x * BN, m0 = blockIdx.y * BM;
  int tid = threadIdx.x;
  int wave = tid >> 6, lane = tid & 63, quad = lane >> 4, l16 = lane & 15;
  int wm = (wave >> 1) * WM, wn = (wave & 1) * WN;

  floatx4 acc[WM / 16][WN / 16];
  #pragma unroll
  for (int i = 0; i < WM / 16; i++)
    #pragma unroll
    for (int j = 0; j < WN / 16; j++) acc[i][j] = (floatx4){0.f, 0.f, 0.f, 0.f};

  // staging decode (chunk linear index = it*256 + tid)
  int srow[4], skc[4];
  #pragma unroll
  for (int it = 0; it < 4; it++) {
    int c = it * 256 + tid;
    srow[it] = c >> 3;
    skc[it] = (c & 7) ^ (srow[it] & 7);
  }

  int kbeg = blockIdx.z * klen;
  for (int k0 = kbeg; k0 < kbeg + klen; k0 += 64) {
    __syncthreads();
    #pragma unroll
    for (int it = 0; it < BM / 32; it++)
      GLD16(A + (size_t)(m0 + srow[it]) * K + k0 + skc[it] * 8,
            As + (it * 2048 + wave * 512));
    #pragma unroll
    for (int it = 0; it < BN / 32; it++)
      GLD16(Bt + (size_t)(n0 + srow[it]) * K + k0 + skc[it] * 8,
            Bs + (it * 2048 + wave * 512));
    __syncthreads();
    #pragma unroll
    for (int kh = 0; kh < 2; kh++) {
      short8 af[WM / 16], bfr[WN / 16];
      int kc = kh * 4 + quad;
      #pragma unroll
      for (int i = 0; i < WM / 16; i++) {
        int ra = wm + i * 16 + l16;
        af[i] = *(const short8*)(As + (ra * 8 + (kc ^ (ra & 7))) * 8);
      }
      #pragma unroll
      for (int j = 0; j < WN / 16; j++) {
        int rb = wn + j * 16 + l16;
        bfr[j] = *(const short8*)(Bs + (rb * 8 + (kc ^ (rb & 7))) * 8);
      }
      #pragma unroll
      for (int i = 0; i < WM / 16; i++)
        #pragma unroll
        for (int j = 0; j < WN / 16; j++)
          acc[i][j] = __builtin_amdgcn_mfma_f32_16x16x32_bf16(af[i], bfr[j], acc[i][j], 0, 0, 0);
    }
  }

  float* Cfz = Cf ? Cf + (size_t)blockIdx.z * M * N : nullptr;
  // C/D: col = l16, row = quad*4 + reg
  #pragma unroll
  for (int i = 0; i < WM / 16; i++) {
    int row = m0 + wm + i * 16 + quad * 4;
    #pragma unroll
    for (int j = 0; j < WN / 16; j++) {
      int col = n0 + wn + j * 16 + l16;
      if (col < N) {
        float bb = bias ? bias[col] : 0.f;
        #pragma unroll
        for (int r = 0; r < 4; r++) {
          float val = acc[i][j][r] + bb;
          if (relu) val = fmaxf(val, 0.f);
          size_t off = (size_t)(row + r) * N + col;
          if (Cfz) Cfz[off] = val;
          if (WVT && col >= 1536) {
            // V^T: vt[((b*12+h)*64+dh)*512 + s]
            int vc = col - 1536;
            int vrow = ((row >> 9) * Hv + (vc >> 6)) * 64 + (vc & 63);
            vt[(size_t)vrow * 512 + (row & 511) + r] = f2b(val);
          } else if (Cb) {
            Cb[off] = f2b(val);
          }
        }
      }
    }
  }
}

// ---------------- fused attention: O = softmax(scale*Q K^T) V --------------------------------
// Phase 1: per-wave 16x512 scores in regs + online softmax (K rows direct from qkv).
// Phase 2: P -> wave-private swizzled LDS (A-layout); B-frags direct from vt (V^T).
// ZERO __syncthreads.
__global__ __launch_bounds__(256) void attn_fused(
    const short* __restrict__ qkv, const short* __restrict__ vt,
    short* __restrict__ O)
{
  __shared__ __align__(16) short pb[4 * 16 * 512];   // 64 KB, wave-private quarters
  int q0 = blockIdx.x * 64;
  int bh = blockIdx.y;
  int b = bh / Hv, h = bh - b * Hv;
  int tid = threadIdx.x;
  int wave = tid >> 6, lane = tid & 63, quad = lane >> 4, l16 = lane & 15;

  floatx4 acc[32];
  #pragma unroll
  for (int c = 0; c < 32; c++) acc[c] = (floatx4){0.f, 0.f, 0.f, 0.f};

  const short* Qrow = qkv + (size_t)(b * Sv + q0 + wave * 16 + l16) * QKVN + h * DHv;
  short8 a0 = *(const short8*)(Qrow + quad * 8);
  short8 a1 = *(const short8*)(Qrow + 32 + quad * 8);
  const short* Kbase = qkv + Dv + (size_t)(b * Sv + l16) * QKVN + h * DHv + quad * 8;
  #pragma unroll
  for (int c = 0; c < 32; c++) {
    const short* Kp = Kbase + (size_t)c * 16 * QKVN;
    short8 b0 = *(const short8*)(Kp);
    short8 b1 = *(const short8*)(Kp + 32);
    acc[c] = __builtin_amdgcn_mfma_f32_16x16x32_bf16(a0, b0, acc[c], 0, 0, 0);
    acc[c] = __builtin_amdgcn_mfma_f32_16x16x32_bf16(a1, b1, acc[c], 0, 0, 0);
  }

  float inv[4];
  #pragma unroll
  for (int r = 0; r < 4; r++) {
    float m = -1e30f;
    #pragma unroll
    for (int c = 0; c < 32; c++) m = fmaxf(m, acc[c][r]);
    m = fmaxf(m, __shfl_xor(m, 1));
    m = fmaxf(m, __shfl_xor(m, 2));
    m = fmaxf(m, __shfl_xor(m, 4));
    m = fmaxf(m, __shfl_xor(m, 8));
    float s = 0.f;
    #pragma unroll
    for (int c = 0; c < 32; c++) {
      float e = __expf((acc[c][r] - m) * 0.125f);
      acc[c][r] = e; s += e;
    }
    s += __shfl_xor(s, 1);
    s += __shfl_xor(s, 2);
    s += __shfl_xor(s, 4);
    s += __shfl_xor(s, 8);
    inv[r] = 1.f / s;
  }

  // write P into wave-private LDS, A-layout, XOR-swizzled 8-short chunks
  short* myp = pb + wave * 8192;
  #pragma unroll
  for (int c = 0; c < 32; c++) {
    int cc = c * 2 + (l16 >> 3);
    #pragma unroll
    for (int r = 0; r < 4; r++) {
      int row = quad * 4 + r;
      myp[row * 512 + ((cc ^ (row & 7)) << 3) + (l16 & 7)] = f2b(acc[c][r] * inv[r]);
    }
  }

  // Phase 2: O[16x64 per wave] = P @ V, V^T streamed from vt
  floatx4 acc_o[4];
  #pragma unroll
  for (int j = 0; j < 4; j++) acc_o[j] = (floatx4){0.f, 0.f, 0.f, 0.f};
  const short* vbase = vt + (size_t)bh * 64 * 512;
  for (int kb = 0; kb < 16; kb++) {
    int cc = kb * 4 + quad;
    short8 af = *(const short8*)(myp + l16 * 512 + ((cc ^ (l16 & 7)) << 3));
    #pragma unroll
    for (int j = 0; j < 4; j++) {
      short8 bf = *(const short8*)(vbase + (size_t)(j * 16 + l16) * 512 + kb * 32 + quad * 8);
      acc_o[j] = __builtin_amdgcn_mfma_f32_16x16x32_bf16(af, bf, acc_o[j], 0, 0, 0);
    }
  }

  int row = q0 + wave * 16 + quad * 4;
  #pragma unroll
  for (int j = 0; j < 4; j++) {
    int col = h * DHv + j * 16 + l16;
    #pragma unroll
    for (int r = 0; r < 4; r++)
      O[(size_t)(b * Sv + row + r) * Dv + col] = f2b(acc_o[j][r]);
  }
}

// ---------------- residual add (2 split-K partials + bias) + layernorm ----------------
__global__ __launch_bounds__(256) void addln_kernel(
    float* __restrict__ xf, const float* __restrict__ mhp,
    const float* __restrict__ bo, short* __restrict__ xb)
{
  int r = blockIdx.x, t = threadIdx.x;
  size_t base = (size_t)r * Dv;
  float v[3];
  #pragma unroll
  for (int i = 0; i < 3; i++) {
    int d = t + i * 256;
    v[i] = xf[base + d] + mhp[base + d] + mhp[MN + base + d] + bo[d];
  }
  __shared__ float red[256];
  red[t] = v[0] + v[1] + v[2];
  __syncthreads();
  for (int s2 = 128; s2 > 0; s2 >>= 1) { if (t < s2) red[t] += red[t + s2]; __syncthreads(); }
  float mean = red[0] * (1.f / 768.f);
  __syncthreads();
  float sq = 0.f;
  #pragma unroll
  for (int i = 0; i < 3; i++) { float d2 = v[i] - mean; sq += d2 * d2; }
  red[t] = sq;
  __syncthreads();
  for (int s2 = 128; s2 > 0; s2 >>= 1) { if (t < s2) red[t] += red[t + s2]; __syncthreads(); }
  float inv = rsqrtf(red[0] * (1.f / 768.f) + 1e-5f);
  #pragma unroll
  for (int i = 0; i < 3; i++) {
    int d = t + i * 256;
    float o = (v[i] - mean) * inv;
    xf[base + d] = o;
    xb[base + d] = f2b(o);
  }
}

// ---------------- FFN2 split-K combine: x = p0 + p1 + b2 (dual write) ----------------
__global__ __launch_bounds__(256) void combine2_kernel(
    const float* __restrict__ p2, const float* __restrict__ b2,
    float* __restrict__ xf, short* __restrict__ xb)
{
  int r = blockIdx.x, t = threadIdx.x;
  size_t base = (size_t)r * Dv;
  #pragma unroll
  for (int i = 0; i < 3; i++) {
    int d = t + i * 256;
    float val = p2[base + d] + p2[MN + base + d] + b2[d];
    xf[base + d] = val;
    xb[base + d] = f2b(val);
  }
}

// ---------------- gather masked rows ----------------
__global__ __launch_bounds__(256) void gather_kernel(
    const short* __restrict__ xb, const int* __restrict__ idx,
    short* __restrict__ g)
{
  int bm = blockIdx.x;            // b*M + m
  int b = bm >> 6;
  int s = idx[bm];
  for (int d = threadIdx.x; d < Dv; d += 256)
    g[(size_t)bm * Dv + d] = xb[(size_t)(b * Sv + s) * Dv + d];
}

// ---------------- log_softmax over V=30000 ----------------
__global__ __launch_bounds__(256) void lsm_kernel(
    const float* __restrict__ L, float* __restrict__ out)
{
  int r = blockIdx.x, t = threadIdx.x;
  const float* p = L + (size_t)r * Vv;
  float m = -1e30f;
  for (int j = t; j < Vv; j += 256) m = fmaxf(m, p[j]);
  __shared__ float red[256];
  red[t] = m;
  __syncthreads();
  for (int s2 = 128; s2 > 0; s2 >>= 1) { if (t < s2) red[t] = fmaxf(red[t], red[t + s2]); __syncthreads(); }
  m = red[0];
  __syncthreads();
  float s = 0.f;
  for (int j = t; j < Vv; j += 256) s += expf(p[j] - m);
  red[t] = s;
  __syncthreads();
  for (int s2 = 128; s2 > 0; s2 >>= 1) { if (t < s2) red[t] += red[t + s2]; __syncthreads(); }
  float lse = m + logf(red[0]);
  for (int j = t; j < Vv; j += 256) out[(size_t)r * Vv + j] = p[j] - lse;
}

extern "C" void kernel_launch(void* const* d_in, const int* in_sizes, int n_in,
                              void* d_out, int out_size, void* d_ws, size_t ws_size,
                              hipStream_t stream) {
  const float* oh  = (const float*)d_in[0];
  const float* sew = (const float*)d_in[1];
  const float* seb = (const float*)d_in[2];
  const float* wq  = (const float*)d_in[3];  const float* bq = (const float*)d_in[4];
  const float* wk  = (const float*)d_in[5];  const float* bk = (const float*)d_in[6];
  const float* wv  = (const float*)d_in[7];  const float* bv = (const float*)d_in[8];
  const float* wo  = (const float*)d_in[9];  const float* bo = (const float*)d_in[10];
  const float* w1  = (const float*)d_in[11]; const float* b1 = (const float*)d_in[12];
  const float* w2  = (const float*)d_in[13]; const float* b2 = (const float*)d_in[14];
  const float* we  = (const float*)d_in[15]; const float* be = (const float*)d_in[16];
  const int*   idx = (const int*)d_in[17];
  float* out = (float*)d_out;

  // workspace carve (256B aligned)
  char* p = (char*)d_ws;
  auto alloc = [&](size_t bytes) -> char* {
    char* r = p; p += (bytes + 255) & ~(size_t)255; return r;
  };
  const size_t BS = (size_t)Bv * Sv;                       // 2048
  short* wqkv_t = (short*)alloc((size_t)QKVN * Dv * 2);    // [2304][768] bf16
  short* wo_t   = (short*)alloc((size_t)Dv * Dv * 2);      // [768][768]
  short* w1_t   = (short*)alloc((size_t)FFv * Dv * 2);     // [3072][768]
  short* w2_t   = (short*)alloc((size_t)Dv * FFv * 2);     // [768][3072]
  float* bqkv   = (float*)alloc(QKVN * 4);
  short* xb     = (short*)alloc(BS * Dv * 2);              // bf16 trunk mirror
  float* xf     = (float*)alloc(BS * Dv * 4);              // fp32 trunk
  short* vt     = (short*)alloc((size_t)Bv * Hv * 64 * 512 * 2);  // V^T [3072][512]
  short* g      = (short*)alloc((size_t)Bv * Mv * Dv * 2);
  char*  TR     = p;                                        // transient union
  // layer-phase views
  short* qkv   = (short*)TR;                                          // [2048][2304] bf16
  short* o     = (short*)(TR + ((BS * QKVN * 2 + 255) & ~(size_t)255));
  float* mhp   = (float*)((char*)o + ((BS * Dv * 2 + 255) & ~(size_t)255));   // 2 partials
  short* t1    = (short*)((char*)mhp + (2 * BS * Dv * 4 + 255 & ~(size_t)255));
  float* f2p   = (float*)((char*)t1 + ((BS * FFv * 2 + 255) & ~(size_t)255)); // 2 partials
  // final-phase views (alias layer phase; used only after the loop)
  short* we_t = (short*)TR;                                           // [30080][768] bf16
  float* lg   = (float*)(TR + (((size_t)Vpad * Dv * 2 + 255) & ~(size_t)255));

  // ---- one-time weight preprocessing (bf16, transposed) ----
  transpose_w<<<dim3(24, 24), 256, 0, stream>>>(wq, wqkv_t,            Dv, Dv, Dv);
  transpose_w<<<dim3(24, 24), 256, 0, stream>>>(wk, wqkv_t + Dv * Dv,  Dv, Dv, Dv);
  transpose_w<<<dim3(24, 24), 256, 0, stream>>>(wv, wqkv_t + 2*Dv*Dv,  Dv, Dv, Dv);
  transpose_w<<<dim3(24, 24), 256, 0, stream>>>(wo, wo_t,              Dv, Dv, Dv);
  transpose_w<<<dim3(96, 24), 256, 0, stream>>>(w1, w1_t,              Dv, FFv, FFv);
  transpose_w<<<dim3(24, 96), 256, 0, stream>>>(w2, w2_t,              FFv, Dv, Dv);
  pack_bias<<<3, 256, 0, stream>>>(bq, bk, bv, bqkv);

  embed_kernel<<<(int)BS, 256, 0, stream>>>(oh, sew, seb, xf, xb);

  dim3 gQKV(QKVN / 128, (int)BS / 128);      // (18, 16) = 288 blocks
  dim3 gFF(FFv / 128, (int)BS / 128);        // (24, 16) = 384 blocks
  dim3 gSK(Dv / 64, (int)BS / 128, 2);       // (12, 16, 2) = 384 blocks, split-K
  for (int l = 0; l < NLAYERS; l++) {
    gemm_bt<128,128,64,64,true><<<gQKV, 256, 0, stream>>>(
        xb, wqkv_t, bqkv, nullptr, qkv, vt, (int)BS, QKVN, Dv, Dv, 0);
    attn_fused<<<dim3(Sv / 64, Bv * Hv), 256, 0, stream>>>(qkv, vt, o);
    gemm_bt<128,64,64,32,false><<<gSK, 256, 0, stream>>>(
        o, wo_t, nullptr, mhp, nullptr, nullptr, (int)BS, Dv, Dv, Dv / 2, 0);
    addln_kernel<<<(int)BS, 256, 0, stream>>>(xf, mhp, bo, xb);
    gemm_bt<128,128,64,64,false><<<gFF, 256, 0, stream>>>(
        xb, w1_t, b1, nullptr, t1, nullptr, (int)BS, FFv, Dv, Dv, 1);
    gemm_bt<128,64,64,32,false><<<gSK, 256, 0, stream>>>(
        t1, w2_t, nullptr, f2p, nullptr, nullptr, (int)BS, Dv, FFv, FFv / 2, 0);
    combine2_kernel<<<(int)BS, 256, 0, stream>>>(f2p, b2, xf, xb);
  }

  // vocab projection (we_t aliases the dead layer buffers)
  transpose_w<<<dim3(940, 24), 256, 0, stream>>>(we, we_t, Dv, Vv, Vpad);
  gather_kernel<<<Bv * Mv, 256, 0, stream>>>(xb, idx, g);
  gemm_bt<128,128,64,64,false><<<dim3(Vpad / 128, (Bv * Mv) / 128), 256, 0, stream>>>(
      g, we_t, be, lg, nullptr, nullptr, Bv * Mv, Vv, Dv, Dv, 0);
  lsm_kernel<<<Bv * Mv, 256, 0, stream>>>(lg, out);
}